// Round 5
// baseline (21582.442 us; speedup 1.0000x reference)
//
#include <hip/hip_runtime.h>
#include <math.h>

#define BB 32
#define TT 2048
#define FF 16
#define CC 17
#define HH 64

typedef float v2f __attribute__((ext_vector_type(2)));
typedef float v4f __attribute__((ext_vector_type(4)));
typedef unsigned int v4u __attribute__((ext_vector_type(4)));
typedef _Float16 h2 __attribute__((ext_vector_type(2)));

__device__ __forceinline__ float rl(float v, int lane) {
    return __int_as_float(__builtin_amdgcn_readlane(__float_as_int(v), lane));
}
__device__ __forceinline__ float uf(float v) {
    return __int_as_float(__builtin_amdgcn_readfirstlane(__float_as_int(v)));
}
__device__ __forceinline__ float ftanh(float x) {
    float e = __builtin_amdgcn_exp2f(x * 2.88539008177792681472f); // exp(2x)
    return 1.0f - 2.0f * __builtin_amdgcn_rcpf(e + 1.0f);
}
__device__ __forceinline__ float fdot2(unsigned int a, unsigned int b, float c) {
    h2 ha = __builtin_bit_cast(h2, a), hb = __builtin_bit_cast(h2, b);
    return __builtin_amdgcn_fdot2(ha, hb, c, false);
}
__device__ __forceinline__ unsigned int packf16(float a, float b) {
    h2 p; p.x = (_Float16)a; p.y = (_Float16)b;   // RN, init-time only
    return __builtin_bit_cast(unsigned int, p);
}
// LDS-only barrier: no vmcnt(0) drain (cross-wave data flows through LDS only;
// global loads/stores in the scan never feed LDS, so draining them is waste).
__device__ __forceinline__ void bar_lds() {
    asm volatile("s_waitcnt lgkmcnt(0)\n\ts_barrier" ::: "memory");
}
#define PIN(v) asm volatile("" : "+v"(v))

// 16 blocks x 512 threads; block handles batch elements eA=2*bid, eB=2*bid+1.
// Wave w owns k-slice [8w,8w+8) of hidden matrices (from LDS) and out columns
// (2w,2w+1) as packed-f16 registers, shared by both batch elements.
__launch_bounds__(512, 2)
__global__ void ncde_main(const float* __restrict__ x,
                          const float* __restrict__ wi1, const float* __restrict__ bi1,
                          const float* __restrict__ wi2, const float* __restrict__ bi2,
                          const float* __restrict__ w_in, const float* __restrict__ b_in,
                          const float* __restrict__ w_hid, const float* __restrict__ b_hid,
                          const float* __restrict__ w_out, const float* __restrict__ b_out,
                          float* __restrict__ zT)
{
    const int bid = blockIdx.x;
    const int eA = 2 * bid, eB = 2 * bid + 1;
    const int tid = threadIdx.x;
    const int w   = tid >> 6;
    const int l   = tid & 63;

    __shared__ float Wl[4][64][64];                   // 64 KB hidden weights [layer][k][h]
    __shared__ v2f  ph[4][8][64];                     // (A,B) hidden partials
    __shared__ __align__(16) unsigned int hb16[64];   // h/256 f16x2: A in [0,32), B in [32,64)
    __shared__ v4f  pgq[8][64];                       // (pgA, a16A, pgB, a16B) partials

    // ---- stage hidden weights into LDS ----
    {
        float* wl = (float*)Wl;
        for (int i = tid; i < 64 * 64; i += 512)     wl[i] = w_in[i];
        for (int i = tid; i < 3 * 64 * 64; i += 512) wl[64 * 64 + i] = w_hid[i];
    }

    float bfold[4];
    bfold[0] = (w == 0) ? b_in[l] : 0.0f;
    bfold[1] = (w == 0) ? b_hid[0 * HH + l] : 0.0f;
    bfold[2] = (w == 0) ? b_hid[1 * HH + l] : 0.0f;
    bfold[3] = (w == 0) ? b_hid[2 * HH + l] : 0.0f;

    const int c0 = 2 * w, c1 = 2 * w + 1;
    unsigned int wo0p[32], wo1p[32], w16p[4];
    #pragma unroll
    for (int j = 0; j < 32; ++j) {
        wo0p[j] = packf16(w_out[(2 * j) * (CC * HH) + l * CC + c0],
                          w_out[(2 * j + 1) * (CC * HH) + l * CC + c0]);
        wo1p[j] = packf16(w_out[(2 * j) * (CC * HH) + l * CC + c1],
                          w_out[(2 * j + 1) * (CC * HH) + l * CC + c1]);
    }
    #pragma unroll
    for (int j = 0; j < 4; ++j)
        w16p[j] = packf16(w_out[(8 * w + 2 * j) * (CC * HH) + l * CC + 16],
                          w_out[(8 * w + 2 * j + 1) * (CC * HH) + l * CC + 16]);
    float bo0  = b_out[l * CC + c0];
    float bo1  = b_out[l * CC + c1];
    float bo16 = b_out[l * CC + 16];

    #pragma unroll
    for (int j = 0; j < 32; ++j) { PIN(wo0p[j]); PIN(wo1p[j]); }
    #pragma unroll
    for (int j = 0; j < 4; ++j) PIN(w16p[j]);

    __syncthreads();   // Wl staged (full barrier once, outside hot loop)

    // ---- z0 for both elements ----
    float zA, zB;
    {
        float h0A = bi1[l], h0B = bi1[l];
        #pragma unroll
        for (int c = 1; c < CC; ++c) {
            float w1 = wi1[c * HH + l];
            h0A = fmaf(x[(size_t)eA * TT * FF + (c - 1)], w1, h0A);
            h0B = fmaf(x[(size_t)eB * TT * FF + (c - 1)], w1, h0B);
        }
        h0A = fmaxf(h0A, 0.0f); h0B = fmaxf(h0B, 0.0f);
        zA = bi2[l]; zB = zA;
        #pragma unroll
        for (int k = 0; k < 64; ++k) {
            float w2 = wi2[k * HH + l];
            zA = fmaf(rl(h0A, k), w2, zA);
            zB = fmaf(rl(h0B, k), w2, zB);
        }
    }
    if (w == 0) {
        zT[(size_t)eA * TT * HH + l] = zA;
        zT[(size_t)eB * TT * HH + l] = zB;
    }

    // ---- fused g() for both elements ----
    auto G2 = [&](float ziA, float ziB,
                  float xa0, float xa1, float xa16,
                  float xb0, float xb1, float xb16) -> v2f {
        float cA = ziA, cB = ziB;
        #pragma unroll
        for (int layer = 0; layer < 4; ++layer) {
            float pA  = bfold[layer], pB  = bfold[layer];
            float pA2 = 0.0f,         pB2 = 0.0f;
            #pragma unroll
            for (int kk = 0; kk < 8; kk += 2) {
                float wk0 = Wl[layer][8 * w + kk][l];
                float wk1 = Wl[layer][8 * w + kk + 1][l];
                float sA0 = rl(cA, 8 * w + kk), sA1 = rl(cA, 8 * w + kk + 1);
                float sB0 = rl(cB, 8 * w + kk), sB1 = rl(cB, 8 * w + kk + 1);
                pA  = fmaf(sA0, wk0, pA);
                pA2 = fmaf(sA1, wk1, pA2);
                pB  = fmaf(sB0, wk0, pB);
                pB2 = fmaf(sB1, wk1, pB2);
            }
            ph[layer][w][l] = (v2f){ pA + pA2, pB + pB2 };
            bar_lds();
            v2f r0 = ph[layer][0][l], r1 = ph[layer][1][l];
            v2f r2 = ph[layer][2][l], r3 = ph[layer][3][l];
            v2f r4 = ph[layer][4][l], r5 = ph[layer][5][l];
            v2f r6 = ph[layer][6][l], r7 = ph[layer][7][l];
            v2f s = ((r0 + r1) + (r2 + r3)) + ((r4 + r5) + (r6 + r7));
            cA = fmaxf(s.x, 0.0f); cB = fmaxf(s.y, 0.0f);
        }
        // publish h/256 as f16x2 (wave 0)
        float pmA = __shfl_xor(cA, 1), pmB = __shfl_xor(cB, 1);
        if (w == 0 && (l & 1) == 0) {
            hb16[l >> 1] = __builtin_bit_cast(unsigned int,
                __builtin_amdgcn_cvt_pkrtz(cA * 0.00390625f, pmA * 0.00390625f));
            hb16[32 + (l >> 1)] = __builtin_bit_cast(unsigned int,
                __builtin_amdgcn_cvt_pkrtz(cB * 0.00390625f, pmB * 0.00390625f));
        }
        bar_lds();

        float uA0a = 0.f, uA0b = 0.f, uA1a = 0.f, uA1b = 0.f;
        float uB0a = 0.f, uB0b = 0.f, uB1a = 0.f, uB1b = 0.f;
        #pragma unroll
        for (int j = 0; j < 8; ++j) {
            v4u qA = *reinterpret_cast<const v4u*>(&hb16[4 * j]);
            v4u qB = *reinterpret_cast<const v4u*>(&hb16[32 + 4 * j]);
            uA0a = fdot2(qA.x, wo0p[4 * j + 0], uA0a);
            uA0b = fdot2(qA.y, wo0p[4 * j + 1], uA0b);
            uA0a = fdot2(qA.z, wo0p[4 * j + 2], uA0a);
            uA0b = fdot2(qA.w, wo0p[4 * j + 3], uA0b);
            uA1a = fdot2(qA.x, wo1p[4 * j + 0], uA1a);
            uA1b = fdot2(qA.y, wo1p[4 * j + 1], uA1b);
            uA1a = fdot2(qA.z, wo1p[4 * j + 2], uA1a);
            uA1b = fdot2(qA.w, wo1p[4 * j + 3], uA1b);
            uB0a = fdot2(qB.x, wo0p[4 * j + 0], uB0a);
            uB0b = fdot2(qB.y, wo0p[4 * j + 1], uB0b);
            uB0a = fdot2(qB.z, wo0p[4 * j + 2], uB0a);
            uB0b = fdot2(qB.w, wo0p[4 * j + 3], uB0b);
            uB1a = fdot2(qB.x, wo1p[4 * j + 0], uB1a);
            uB1b = fdot2(qB.y, wo1p[4 * j + 1], uB1b);
            uB1a = fdot2(qB.z, wo1p[4 * j + 2], uB1a);
            uB1b = fdot2(qB.w, wo1p[4 * j + 3], uB1b);
        }
        // c=16 column, this wave's k-slice
        v4u qcA = *reinterpret_cast<const v4u*>(&hb16[4 * w]);
        v4u qcB = *reinterpret_cast<const v4u*>(&hb16[32 + 4 * w]);
        float aA16 = fdot2(qcA.x, w16p[0], fdot2(qcA.z, w16p[2], 0.0f));
        float aA16b = fdot2(qcA.y, w16p[1], fdot2(qcA.w, w16p[3], 0.0f));
        float aB16 = fdot2(qcB.x, w16p[0], fdot2(qcB.z, w16p[2], 0.0f));
        float aB16b = fdot2(qcB.y, w16p[1], fdot2(qcB.w, w16p[3], 0.0f));

        float u0A = fmaf(uA0a + uA0b, 256.0f, bo0);
        float u1A = fmaf(uA1a + uA1b, 256.0f, bo1);
        float u0B = fmaf(uB0a + uB0b, 256.0f, bo0);
        float u1B = fmaf(uB1a + uB1b, 256.0f, bo1);
        float pgA = ftanh(u0A) * xa0 + ftanh(u1A) * xa1;
        float pgB = ftanh(u0B) * xb0 + ftanh(u1B) * xb1;
        pgq[w][l] = (v4f){ pgA, aA16 + aA16b, pgB, aB16 + aB16b };
        bar_lds();
        v4f s0 = pgq[0][l], s1 = pgq[1][l], s2 = pgq[2][l], s3 = pgq[3][l];
        v4f s4 = pgq[4][l], s5 = pgq[5][l], s6 = pgq[6][l], s7 = pgq[7][l];
        v4f st = ((s0 + s1) + (s2 + s3)) + ((s4 + s5) + (s6 + s7));
        float u16A = fmaf(st.y, 256.0f, bo16);
        float u16B = fmaf(st.w, 256.0f, bo16);
        return (v2f){ fmaf(ftanh(u16A), xa16, st.x),
                      fmaf(ftanh(u16B), xb16, st.z) };
    };

    // ---- time scan (uniform scalars in SGPRs via uf) ----
    const float* xA = x + (size_t)eA * TT * FF;
    const float* xB = x + (size_t)eB * TT * FF;
    const bool hasc0 = (w != 0);
    const int  f0 = 2 * w - 1;
    const int  f1 = 2 * w;

    float xpA0 = hasc0 ? uf(xA[f0]) : 0.0f, xpA1 = uf(xA[f1]), xpA16 = uf(xA[15]);
    float xpB0 = hasc0 ? uf(xB[f0]) : 0.0f, xpB1 = uf(xB[f1]), xpB16 = uf(xB[15]);
    float xnA0 = hasc0 ? uf(xA[FF + f0]) : 0.0f, xnA1 = uf(xA[FF + f1]), xnA16 = uf(xA[FF + 15]);
    float xnB0 = hasc0 ? uf(xB[FF + f0]) : 0.0f, xnB1 = uf(xB[FF + f1]), xnB16 = uf(xB[FF + 15]);
    float dcA0 = hasc0 ? (xnA0 - xpA0) : 1.0f, dcA1 = xnA1 - xpA1, dcA16 = xnA16 - xpA16;
    float dcB0 = hasc0 ? (xnB0 - xpB0) : 1.0f, dcB1 = xnB1 - xpB1, dcB16 = xnB16 - xpB16;
    float dpA0 = dcA0, dpA1 = dcA1, dpA16 = dcA16;
    float dpB0 = dcB0, dpB1 = dcB1, dpB16 = dcB16;
    xpA0 = xnA0; xpA1 = xnA1; xpA16 = xnA16;
    xpB0 = xnB0; xpB1 = xnB1; xpB16 = xnB16;

    #pragma unroll 1
    for (int t = 0; t < TT - 1; ++t) {
        const float f43 = 4.0f / 3.0f;
        float x2A0 = dpA0 + f43 * (dcA0 - dpA0);
        float x2A1 = dpA1 + f43 * (dcA1 - dpA1);
        float x2A16 = dpA16 + f43 * (dcA16 - dpA16);
        float x2B0 = dpB0 + f43 * (dcB0 - dpB0);
        float x2B1 = dpB1 + f43 * (dcB1 - dpB1);
        float x2B16 = dpB16 + f43 * (dcB16 - dpB16);

        int tn = (t + 2 < TT) ? (t + 2) : (TT - 1);
        float ynA0 = hasc0 ? uf(xA[tn * FF + f0]) : 0.0f;
        float ynA1 = uf(xA[tn * FF + f1]);
        float ynA16 = uf(xA[tn * FF + 15]);
        float ynB0 = hasc0 ? uf(xB[tn * FF + f0]) : 0.0f;
        float ynB1 = uf(xB[tn * FF + f1]);
        float ynB16 = uf(xB[tn * FF + 15]);

        v2f k1 = G2(zA, zB, dpA0, dpA1, dpA16, dpB0, dpB1, dpB16);
        v2f k2 = G2(zA + k1.x * (1.0f / 3.0f), zB + k1.y * (1.0f / 3.0f),
                    dcA0, dcA1, dcA16, dcB0, dcB1, dcB16);
        v2f k3 = G2(zA + (k2.x - k1.x * (1.0f / 3.0f)), zB + (k2.y - k1.y * (1.0f / 3.0f)),
                    x2A0, x2A1, x2A16, x2B0, x2B1, x2B16);
        v2f k4 = G2(zA + (k1.x - k2.x + k3.x), zB + (k1.y - k2.y + k3.y),
                    dcA0, dcA1, dcA16, dcB0, dcB1, dcB16);
        zA += 0.125f * (k1.x + 3.0f * (k2.x + k3.x) + k4.x);
        zB += 0.125f * (k1.y + 3.0f * (k2.y + k3.y) + k4.y);

        if (w == 0) {
            zT[((size_t)eA * TT + t + 1) * HH + l] = zA;
            zT[((size_t)eB * TT + t + 1) * HH + l] = zB;
        }

        dpA0 = dcA0; dpA1 = dcA1; dpA16 = dcA16;
        dpB0 = dcB0; dpB1 = dcB1; dpB16 = dcB16;
        dcA0 = hasc0 ? (ynA0 - xpA0) : 1.0f;
        dcA1 = ynA1 - xpA1; dcA16 = ynA16 - xpA16;
        dcB0 = hasc0 ? (ynB0 - xpB0) : 1.0f;
        dcB1 = ynB1 - xpB1; dcB16 = ynB16 - xpB16;
        xpA0 = ynA0; xpA1 = ynA1; xpA16 = ynA16;
        xpB0 = ynB0; xpB1 = ynB1; xpB16 = ynB16;
    }
}

// out = gelu_exact(zT) @ w_proj + b_proj ; mask = 0
__global__ void ncde_proj(const float* __restrict__ zT,
                          const float* __restrict__ w_proj, const float* __restrict__ b_proj,
                          float* __restrict__ out, float* __restrict__ mask)
{
    __shared__ float gz[16][64];
    const int blk = blockIdx.x;
    const int tid = threadIdx.x;
    const int r16 = tid >> 4, f = tid & 15;
    const int row0 = blk * 16;

    #pragma unroll
    for (int i = 0; i < 4; ++i) {
        int idx = tid + i * 256;
        int r = idx >> 6, k = idx & 63;
        float zv = zT[(size_t)(row0 + r) * HH + k];
        gz[r][k] = 0.5f * zv * (1.0f + erff(zv * 0.70710678118654752f));
    }
    __syncthreads();

    float acc = b_proj[f];
    #pragma unroll
    for (int k = 0; k < 64; ++k)
        acc = fmaf(gz[r16][k], w_proj[k * FF + f], acc);
    out[(size_t)(row0 + r16) * FF + f] = acc;
    if (f == 0) mask[row0 + r16] = 0.0f;
}

extern "C" void kernel_launch(void* const* d_in, const int* in_sizes, int n_in,
                              void* d_out, int out_size, void* d_ws, size_t ws_size,
                              hipStream_t stream)
{
    (void)in_sizes; (void)n_in; (void)d_ws; (void)ws_size; (void)out_size;
    const float* x      = (const float*)d_in[0];
    const float* wi1    = (const float*)d_in[1];
    const float* bi1    = (const float*)d_in[2];
    const float* wi2    = (const float*)d_in[3];
    const float* bi2    = (const float*)d_in[4];
    const float* w_in   = (const float*)d_in[5];
    const float* b_in   = (const float*)d_in[6];
    const float* w_hid  = (const float*)d_in[7];
    const float* b_hid  = (const float*)d_in[8];
    const float* w_out  = (const float*)d_in[9];
    const float* b_out  = (const float*)d_in[10];
    const float* w_proj = (const float*)d_in[11];
    const float* b_proj = (const float*)d_in[12];

    float* zT   = (float*)d_out;                       // B*T*H
    float* outp = zT + (size_t)BB * TT * HH;           // B*T*F
    float* mask = outp + (size_t)BB * TT * FF;         // B*T

    ncde_main<<<dim3(BB / 2), dim3(512), 0, stream>>>(
        x, wi1, bi1, wi2, bi2, w_in, b_in, w_hid, b_hid, w_out, b_out, zT);
    ncde_proj<<<dim3((BB * TT) / 16), dim3(256), 0, stream>>>(
        zT, w_proj, b_proj, outp, mask);
}

// Round 6
// 15815.805 us; speedup vs baseline: 1.3646x; 1.3646x over previous
//
#include <hip/hip_runtime.h>
#include <math.h>

#define BB 32
#define TT 2048
#define FF 16
#define CC 17
#define HH 64

typedef float v2f __attribute__((ext_vector_type(2)));
typedef float v4f __attribute__((ext_vector_type(4)));
typedef unsigned int v4u __attribute__((ext_vector_type(4)));
typedef _Float16 h2 __attribute__((ext_vector_type(2)));

__device__ __forceinline__ float rl(float v, int lane) {
    return __int_as_float(__builtin_amdgcn_readlane(__float_as_int(v), lane));
}
__device__ __forceinline__ float uf(float v) {
    return __int_as_float(__builtin_amdgcn_readfirstlane(__float_as_int(v)));
}
__device__ __forceinline__ float ftanh(float x) {
    float e = __builtin_amdgcn_exp2f(x * 2.88539008177792681472f); // exp(2x)
    return 1.0f - 2.0f * __builtin_amdgcn_rcpf(e + 1.0f);
}
__device__ __forceinline__ float fdot2(unsigned int a, unsigned int b, float c) {
    h2 ha = __builtin_bit_cast(h2, a), hb = __builtin_bit_cast(h2, b);
    return __builtin_amdgcn_fdot2(ha, hb, c, false);
}
// LDS-only barrier: no vmcnt(0) drain.
__device__ __forceinline__ void bar_lds() {
    asm volatile("s_waitcnt lgkmcnt(0)\n\ts_barrier" ::: "memory");
}
#define PIN(v) asm volatile("" : "+v"(v))

// One block per batch element, 8 waves.
// Hidden chain: wave 0 SOLO (no barriers needed within a wave; DS ops are
// program-ordered). Out layer: 8-way split (wave w owns columns 2w,2w+1 and
// k-slice of c=16), f16 dot2 as in R4. Only TWO s_barrier per G-call
// (R1-R5 post-mortems: 6 barrier segments x ~500-700cy round trips were the
// wall, not VALU issue).
__launch_bounds__(512)
__global__ void ncde_main(const float* __restrict__ x,
                          const float* __restrict__ wi1, const float* __restrict__ bi1,
                          const float* __restrict__ wi2, const float* __restrict__ bi2,
                          const float* __restrict__ w_in, const float* __restrict__ b_in,
                          const float* __restrict__ w_hid, const float* __restrict__ b_hid,
                          const float* __restrict__ w_out, const float* __restrict__ b_out,
                          float* __restrict__ zT)
{
    const int b   = blockIdx.x;
    const int tid = threadIdx.x;
    const int w   = tid >> 6;
    const int l   = tid & 63;

    // Hidden weights transposed: WT[layer][h][k], row stride 66 floats.
    // Bank index for lane l reading (l*66 + k): (2l+2k)%32 -> 2 lanes/bank (free).
    __shared__ float WT[4 * 64 * 66];
    __shared__ __align__(16) float hf[64];           // hidden activation (f32)
    __shared__ __align__(16) unsigned int hb16[32];  // h*2^-8 packed f16x2 (for out layer)
    __shared__ v2f pgq[8][64];                       // (pg, a16) partials per wave

    // ---- stage WT ----
    for (int i = tid; i < 4 * 64 * 64; i += 512) {
        int layer = i >> 12, r = i & 4095, h = r >> 6, k = r & 63;
        float v = (layer == 0) ? w_in[k * HH + h]
                               : w_hid[((layer - 1) * HH + k) * HH + h];
        WT[layer * (64 * 66) + h * 66 + k] = v;
    }

    // wave-0 biases (one per lane)
    float bh0 = b_in[l];
    float bh1 = b_hid[0 * HH + l];
    float bh2 = b_hid[1 * HH + l];
    float bh3 = b_hid[2 * HH + l];

    const int c0 = 2 * w, c1 = 2 * w + 1;
    unsigned int wo0p[32], wo1p[32], w16p[4];
    #pragma unroll
    for (int j = 0; j < 32; ++j) {
        h2 p0; p0.x = (_Float16)w_out[(2 * j) * (CC * HH) + l * CC + c0];
        p0.y = (_Float16)w_out[(2 * j + 1) * (CC * HH) + l * CC + c0];
        wo0p[j] = __builtin_bit_cast(unsigned int, p0);
        h2 p1; p1.x = (_Float16)w_out[(2 * j) * (CC * HH) + l * CC + c1];
        p1.y = (_Float16)w_out[(2 * j + 1) * (CC * HH) + l * CC + c1];
        wo1p[j] = __builtin_bit_cast(unsigned int, p1);
    }
    #pragma unroll
    for (int j = 0; j < 4; ++j) {
        h2 p; p.x = (_Float16)w_out[(8 * w + 2 * j) * (CC * HH) + l * CC + 16];
        p.y = (_Float16)w_out[(8 * w + 2 * j + 1) * (CC * HH) + l * CC + 16];
        w16p[j] = __builtin_bit_cast(unsigned int, p);
    }
    float bo0  = b_out[l * CC + c0];
    float bo1  = b_out[l * CC + c1];
    float bo16 = b_out[l * CC + 16];

    #pragma unroll
    for (int j = 0; j < 32; ++j) { PIN(wo0p[j]); PIN(wo1p[j]); }
    #pragma unroll
    for (int j = 0; j < 4; ++j) PIN(w16p[j]);

    __syncthreads();   // WT staged

    // ---- z0 ----
    float z;
    {
        float h0 = bi1[l];
        #pragma unroll
        for (int c = 1; c < CC; ++c)
            h0 = fmaf(x[(size_t)b * TT * FF + (c - 1)], wi1[c * HH + l], h0);
        h0 = fmaxf(h0, 0.0f);
        z = bi2[l];
        #pragma unroll
        for (int k = 0; k < 64; ++k)
            z = fmaf(rl(h0, k), wi2[k * HH + l], z);
    }
    if (w == 7) zT[(size_t)b * TT * HH + l] = z;

    // ---- g(zin, xd): wave0 solo hidden chain, then 8-way out layer ----
    auto G = [&](float zin, float xd0, float xd1, float xd16) -> float {
        if (w == 0) {
            hf[l] = zin;                 // publish input (wave-internal, no barrier)
            float cur;
            #pragma unroll
            for (int layer = 0; layer < 4; ++layer) {
                const float* WL = &WT[layer * (64 * 66) + l * 66];
                v2f a0 = { 0.f, 0.f }, a1 = { 0.f, 0.f };
                v2f a2 = { 0.f, 0.f }, a3 = { 0.f, 0.f };
                #pragma unroll
                for (int jj = 0; jj < 16; jj += 2) {
                    v4f q0 = *reinterpret_cast<const v4f*>(&hf[4 * jj]);      // uniform
                    v4f q1 = *reinterpret_cast<const v4f*>(&hf[4 * jj + 4]);  // uniform
                    v2f w00 = *reinterpret_cast<const v2f*>(&WL[4 * jj]);
                    v2f w01 = *reinterpret_cast<const v2f*>(&WL[4 * jj + 2]);
                    v2f w10 = *reinterpret_cast<const v2f*>(&WL[4 * jj + 4]);
                    v2f w11 = *reinterpret_cast<const v2f*>(&WL[4 * jj + 6]);
                    a0 += w00 * (v2f){ q0.x, q0.y };
                    a1 += w01 * (v2f){ q0.z, q0.w };
                    a2 += w10 * (v2f){ q1.x, q1.y };
                    a3 += w11 * (v2f){ q1.z, q1.w };
                }
                v2f s = (a0 + a1) + (a2 + a3);
                float bias = (layer == 0) ? bh0 : (layer == 1) ? bh1 : (layer == 2) ? bh2 : bh3;
                cur = fmaxf(s.x + s.y + bias, 0.0f);
                if (layer < 3) hf[l] = cur;   // in-place: reads above precede (wave order)
            }
            // publish h*2^-8 as f16 pairs for the out layer
            float sc = cur * 0.00390625f;
            float ot = __shfl_xor(sc, 1);
            if ((l & 1) == 0)
                hb16[l >> 1] = __builtin_bit_cast(unsigned int,
                    __builtin_amdgcn_cvt_pkrtz(sc, ot));
        }
        bar_lds();   // barrier #1: h published

        float u0a = 0.f, u0b = 0.f, u1a = 0.f, u1b = 0.f;
        #pragma unroll
        for (int j = 0; j < 8; ++j) {
            v4u q = *reinterpret_cast<const v4u*>(&hb16[4 * j]);   // uniform broadcast
            u0a = fdot2(q.x, wo0p[4 * j + 0], u0a);
            u0b = fdot2(q.y, wo0p[4 * j + 1], u0b);
            u0a = fdot2(q.z, wo0p[4 * j + 2], u0a);
            u0b = fdot2(q.w, wo0p[4 * j + 3], u0b);
            u1a = fdot2(q.x, wo1p[4 * j + 0], u1a);
            u1b = fdot2(q.y, wo1p[4 * j + 1], u1b);
            u1a = fdot2(q.z, wo1p[4 * j + 2], u1a);
            u1b = fdot2(q.w, wo1p[4 * j + 3], u1b);
        }
        v4u qc = *reinterpret_cast<const v4u*>(&hb16[4 * w]);      // this wave's c16 slice
        float a16a = fdot2(qc.x, w16p[0], fdot2(qc.z, w16p[2], 0.0f));
        float a16b = fdot2(qc.y, w16p[1], fdot2(qc.w, w16p[3], 0.0f));

        float u0 = fmaf(u0a + u0b, 256.0f, bo0);
        float u1 = fmaf(u1a + u1b, 256.0f, bo1);
        float pg = ftanh(u0) * xd0 + ftanh(u1) * xd1;
        pgq[w][l] = (v2f){ pg, a16a + a16b };
        bar_lds();   // barrier #2: partials published

        v2f s0 = pgq[0][l], s1 = pgq[1][l], s2 = pgq[2][l], s3 = pgq[3][l];
        v2f s4 = pgq[4][l], s5 = pgq[5][l], s6 = pgq[6][l], s7 = pgq[7][l];
        v2f st = ((s0 + s1) + (s2 + s3)) + ((s4 + s5) + (s6 + s7));
        float u16 = fmaf(st.y, 256.0f, bo16);
        return fmaf(ftanh(u16), xd16, st.x);
    };

    // ---- time scan ----
    const float* xb = x + (size_t)b * TT * FF;
    const bool hasc0 = (w != 0);
    const int  f0 = 2 * w - 1;
    const int  f1 = 2 * w;
    float xp0  = hasc0 ? uf(xb[f0]) : 0.0f;
    float xp1  = uf(xb[f1]);
    float xp16 = uf(xb[15]);
    float xn0  = hasc0 ? uf(xb[FF + f0]) : 0.0f;
    float xn1  = uf(xb[FF + f1]);
    float xn16 = uf(xb[FF + 15]);
    float dc0  = hasc0 ? (xn0 - xp0) : 1.0f;
    float dc1  = xn1 - xp1;
    float dc16 = xn16 - xp16;
    float dp0 = dc0, dp1 = dc1, dp16 = dc16;
    xp0 = xn0; xp1 = xn1; xp16 = xn16;

    #pragma unroll 1
    for (int t = 0; t < TT - 1; ++t) {
        const float f43 = 4.0f / 3.0f;
        float x20  = dp0  + f43 * (dc0  - dp0);
        float x21  = dp1  + f43 * (dc1  - dp1);
        float x216 = dp16 + f43 * (dc16 - dp16);

        int tn = (t + 2 < TT) ? (t + 2) : (TT - 1);
        float yn0  = hasc0 ? uf(xb[tn * FF + f0]) : 0.0f;
        float yn1  = uf(xb[tn * FF + f1]);
        float yn16 = uf(xb[tn * FF + 15]);

        float k1 = G(z, dp0, dp1, dp16);
        float k2 = G(z + k1 * (1.0f / 3.0f), dc0, dc1, dc16);
        float k3 = G(z + (k2 - k1 * (1.0f / 3.0f)), x20, x21, x216);
        float k4 = G(z + (k1 - k2 + k3), dc0, dc1, dc16);
        z = z + 0.125f * (k1 + 3.0f * (k2 + k3) + k4);

        if (w == 7) zT[((size_t)b * TT + t + 1) * HH + l] = z;

        dp0 = dc0; dp1 = dc1; dp16 = dc16;
        dc0 = hasc0 ? (yn0 - xp0) : 1.0f;
        dc1 = yn1 - xp1;
        dc16 = yn16 - xp16;
        xp0 = yn0; xp1 = yn1; xp16 = yn16;
    }
}

// out = gelu_exact(zT) @ w_proj + b_proj ; mask = 0
__global__ void ncde_proj(const float* __restrict__ zT,
                          const float* __restrict__ w_proj, const float* __restrict__ b_proj,
                          float* __restrict__ out, float* __restrict__ mask)
{
    __shared__ float gz[16][64];
    const int blk = blockIdx.x;
    const int tid = threadIdx.x;
    const int r16 = tid >> 4, f = tid & 15;
    const int row0 = blk * 16;

    #pragma unroll
    for (int i = 0; i < 4; ++i) {
        int idx = tid + i * 256;
        int r = idx >> 6, k = idx & 63;
        float zv = zT[(size_t)(row0 + r) * HH + k];
        gz[r][k] = 0.5f * zv * (1.0f + erff(zv * 0.70710678118654752f));
    }
    __syncthreads();

    float acc = b_proj[f];
    #pragma unroll
    for (int k = 0; k < 64; ++k)
        acc = fmaf(gz[r16][k], w_proj[k * FF + f], acc);
    out[(size_t)(row0 + r16) * FF + f] = acc;
    if (f == 0) mask[row0 + r16] = 0.0f;
}

extern "C" void kernel_launch(void* const* d_in, const int* in_sizes, int n_in,
                              void* d_out, int out_size, void* d_ws, size_t ws_size,
                              hipStream_t stream)
{
    (void)in_sizes; (void)n_in; (void)d_ws; (void)ws_size; (void)out_size;
    const float* x      = (const float*)d_in[0];
    const float* wi1    = (const float*)d_in[1];
    const float* bi1    = (const float*)d_in[2];
    const float* wi2    = (const float*)d_in[3];
    const float* bi2    = (const float*)d_in[4];
    const float* w_in   = (const float*)d_in[5];
    const float* b_in   = (const float*)d_in[6];
    const float* w_hid  = (const float*)d_in[7];
    const float* b_hid  = (const float*)d_in[8];
    const float* w_out  = (const float*)d_in[9];
    const float* b_out  = (const float*)d_in[10];
    const float* w_proj = (const float*)d_in[11];
    const float* b_proj = (const float*)d_in[12];

    float* zT   = (float*)d_out;                       // B*T*H
    float* outp = zT + (size_t)BB * TT * HH;           // B*T*F
    float* mask = outp + (size_t)BB * TT * FF;         // B*T

    ncde_main<<<dim3(BB), dim3(512), 0, stream>>>(
        x, wi1, bi1, wi2, bi2, w_in, b_in, w_hid, b_hid, w_out, b_out, zT);
    ncde_proj<<<dim3((BB * TT) / 16), dim3(256), 0, stream>>>(
        zT, w_proj, b_proj, outp, mask);
}